// Round 5
// baseline (776.201 us; speedup 1.0000x reference)
//
#include <hip/hip_runtime.h>

#define SEQ    2048
#define BATCH  16
#define HID    1024
#define M_TOT  (SEQ*BATCH)      // 32768 rows
#define NCH    (BATCH*HID)      // 16384 scan channels
#define NSEG1  256              // layer-1: 8-timestep segments (one per gemm1 bm tile)
#define NSEG   128              // layer-2: 16-timestep segments (one per gemm2 bm tile)

typedef __attribute__((ext_vector_type(8))) short          short8;
typedef __attribute__((ext_vector_type(8))) unsigned short ushort8_t;
typedef __attribute__((ext_vector_type(4))) float          floatx4;

__device__ __forceinline__ unsigned short f32_to_bf16(float f) {
  unsigned int u = __float_as_uint(f);
  u += 0x7FFFu + ((u >> 16) & 1u);           // round-to-nearest-even
  return (unsigned short)(u >> 16);
}
__device__ __forceinline__ float bf16_to_f32(unsigned short h) {
  return __uint_as_float(((unsigned int)h) << 16);
}
__device__ __forceinline__ float sigmoidf_(float x) {
  return 1.f / (1.f + __expf(-x));
}

// ============================================================================
// Swizzled operand layout ("fragment image"):
//   (R rows, K cols) bf16 -> blocks of 128 rows x 32 k = 4096 ushorts.
//   block = (row>>7)*(K/32) + (k>>5).  Within a block, for (r=row&127, kk=k&31):
//     unit = (r>>4)*64 + ((kk>>3)<<4) + (r&15);  ushort off = unit*8 + (kk&7)
//   MFMA fragment for rows j*16..j*16+15 = 1 KB at off j*512; lane l's 16B at
//   j*512 + l*8 -> direct global_load_dwordx4 / global_load_lds_dwordx4,
//   fully coalesced, and bank-conflict-free when re-read from LDS.
// ============================================================================

// ---------------- prep bodies (fused into one launch) -----------------------
__device__ __forceinline__ void cast_swizzle_body(const float* __restrict__ src,
    unsigned short* __restrict__ dst, int mt, int kt, int t) {
  __shared__ unsigned short tile[4096];
  const int r = t >> 1, kh = (t & 1) * 16;
  const float* sp = src + (size_t)(mt * 128 + r) * 1024 + kt * 32 + kh;
  float4 v0 = *(const float4*)(sp + 0);
  float4 v1 = *(const float4*)(sp + 4);
  float4 v2 = *(const float4*)(sp + 8);
  float4 v3 = *(const float4*)(sp + 12);
  ushort8_t u0, u1;
  u0[0]=f32_to_bf16(v0.x); u0[1]=f32_to_bf16(v0.y); u0[2]=f32_to_bf16(v0.z); u0[3]=f32_to_bf16(v0.w);
  u0[4]=f32_to_bf16(v1.x); u0[5]=f32_to_bf16(v1.y); u0[6]=f32_to_bf16(v1.z); u0[7]=f32_to_bf16(v1.w);
  u1[0]=f32_to_bf16(v2.x); u1[1]=f32_to_bf16(v2.y); u1[2]=f32_to_bf16(v2.z); u1[3]=f32_to_bf16(v2.w);
  u1[4]=f32_to_bf16(v3.x); u1[5]=f32_to_bf16(v3.y); u1[6]=f32_to_bf16(v3.z); u1[7]=f32_to_bf16(v3.w);
  const int c = r >> 4, lr = r & 15, q0 = kh >> 3;
  const int unit0 = c * 64 + (q0 << 4) + lr;
  *(ushort8_t*)&tile[unit0 * 8]        = u0;
  *(ushort8_t*)&tile[(unit0 + 16) * 8] = u1;
  __syncthreads();
  const size_t base = ((size_t)mt * 32 + kt) * 4096;
  *(ushort8_t*)&dst[base + t * 16]     = *(const ushort8_t*)&tile[t * 16];
  *(ushort8_t*)&dst[base + t * 16 + 8] = *(const ushort8_t*)&tile[t * 16 + 8];
}

__device__ __forceinline__ void w_prep_body(const float* __restrict__ W,
    unsigned short* __restrict__ Wsw, int nt, int kt, int t) {
  __shared__ unsigned short tile[4096];
  const int kk = t >> 3, n0 = (t & 7) * 16;
  const float* sp = W + (size_t)(kt * 32 + kk) * 3072 + nt * 128 + n0;
  float v[16];
#pragma unroll
  for (int i = 0; i < 16; i += 4) {
    float4 f = *(const float4*)(sp + i);
    v[i] = f.x; v[i+1] = f.y; v[i+2] = f.z; v[i+3] = f.w;
  }
  const int cbase = (n0 >> 4) * 64 + ((kk >> 3) << 4);
#pragma unroll
  for (int j = 0; j < 16; j++)
    tile[(cbase + j) * 8 + (kk & 7)] = f32_to_bf16(v[j]);
  __syncthreads();
  const size_t base = ((size_t)nt * 32 + kt) * 4096;
  *(ushort8_t*)&Wsw[base + t * 16]     = *(const ushort8_t*)&tile[t * 16];
  *(ushort8_t*)&Wsw[base + t * 16 + 8] = *(const ushort8_t*)&tile[t * 16 + 8];
}

// one launch: blocks [0,8192) cast x; [8192,8960) W0; [8960,9728) W1
__global__ __launch_bounds__(256) void prep_all(const float* __restrict__ x,
    const float* __restrict__ W0, const float* __restrict__ W1,
    unsigned short* __restrict__ xsw, unsigned short* __restrict__ W0sw,
    unsigned short* __restrict__ W1sw) {
  const int id = blockIdx.x, t = threadIdx.x;
  if (id < 8192)        cast_swizzle_body(x, xsw, id >> 5, id & 31, t);
  else if (id < 8960)   w_prep_body(W0, W0sw, (id - 8192) >> 5, (id - 8192) & 31, t);
  else                  w_prep_body(W1, W1sw, (id - 8960) >> 5, (id - 8960) & 31, t);
}

// ---------------------------------------------------------------------------
// global_load_lds helper: 16B per lane, wave-uniform LDS base + lane*16 (HW).
// ---------------------------------------------------------------------------
typedef __attribute__((address_space(1))) const unsigned int GUI;
typedef __attribute__((address_space(3))) unsigned int LUI;
__device__ __forceinline__ void gl16(const unsigned short* g, unsigned short* l) {
  __builtin_amdgcn_global_load_lds((GUI*)g, (LUI*)l, 16, 0, 0);
}
// barrier as inline asm with memory clobber: scheduling fence for LDS ops,
// and (unlike __syncthreads) no compiler-inserted vmcnt(0) drain.
__device__ __forceinline__ void barrier_fence() {
  asm volatile("s_barrier" ::: "memory");
}

// ---------------------------------------------------------------------------
// Layer-1 GEMM + fused segment scan (paired-panel form, R2 schedule constants).
//   Block = bm(256 of 128 rows) x bn(8 of 128 cols x 3 panels x/f/r).
//   512 threads, 8 waves: wm(2) x 64 rows, wn(4) x 32 cols.  acc 4mi x 2nj x
//   3 panels = 96 VGPR.  LDS slot = A+Bx+Bf+Br = 32KB, 4-slot ring = 128KB.
//   Stage 3 tiles ahead, 4 gl16/wave/tile, counted vmcnt(8/4/0), one
//   s_barrier per K-tile — identical constants to the proven R2 pipeline.
//   Epilogue: store Xt/F/R (pass2 needs them) + 4-step in-register scan +
//   cross-wm LDS combine -> 8-t segment (Pseg1,Sseg1).  Eliminates the
//   scan_pass1 kernel (128 MB of re-reads).
// ---------------------------------------------------------------------------
__global__ __launch_bounds__(512, 2) void gemm1_scan(
    const unsigned short* __restrict__ A, const unsigned short* __restrict__ B,
    unsigned short* __restrict__ Xt, unsigned short* __restrict__ Fo,
    unsigned short* __restrict__ Ro, const float* __restrict__ bias,
    float* __restrict__ Pseg1, float* __restrict__ Sseg1)
{
  __shared__ unsigned short lds[65536];       // 128 KB = 4 ring slots x 32 KB
  const int tid = threadIdx.x;
  const int wave = tid >> 6, lane = tid & 63;
  const int wm = wave >> 2, wn = wave & 3;    // wm: 64-row half, wn: 32-col quarter
  const int id = blockIdx.x;                  // 2048 blocks
  const int xcd = id & 7, slot = id >> 3;     // 256 slots per xcd
  const int bn = slot >> 5;                   // 0..7   (bm fastest -> B resident)
  const int bm = xcd * 32 + (slot & 31);      // 0..255

  // staging source pointers (per-lane 16B piece of each 8KB chunk)
  const unsigned short* aSrc  = A + ((size_t)bm * 32) * 4096 + tid * 8;
  const unsigned short* bxSrc = B + ((size_t)bn * 32) * 4096 + tid * 8;
  const unsigned short* bfSrc = B + ((size_t)(8 + bn) * 32) * 4096 + tid * 8;
  const unsigned short* brSrc = B + ((size_t)(16 + bn) * 32) * 4096 + tid * 8;

  floatx4 ax[4][2], af[4][2], arr[4][2];
#pragma unroll
  for (int i = 0; i < 4; i++)
#pragma unroll
    for (int j = 0; j < 2; j++)
#pragma unroll
      for (int rr = 0; rr < 4; rr++) { ax[i][j][rr] = 0.f; af[i][j][rr] = 0.f; arr[i][j][rr] = 0.f; }

  // prologue: stage K-tiles 0..2 (12 chunk-loads/wave), drain, barrier
#pragma unroll
  for (int u = 0; u < 3; ++u) {
    unsigned short* d = &lds[u * 16384 + wave * 512];
    gl16(aSrc  + (size_t)u * 4096, d);
    gl16(bxSrc + (size_t)u * 4096, d + 4096);
    gl16(bfSrc + (size_t)u * 4096, d + 8192);
    gl16(brSrc + (size_t)u * 4096, d + 12288);
  }
  asm volatile("s_waitcnt vmcnt(0)" ::: "memory");
  barrier_fence();

  const int aoff = wm * 2048 + lane * 8;           // frags wm*4 .. wm*4+3
  const int bxo  = 4096  + wn * 1024 + lane * 8;   // 2 frags per wave
  const int bfo  = 8192  + wn * 1024 + lane * 8;
  const int bro  = 12288 + wn * 1024 + lane * 8;

  // main loop: one barrier per K-tile; vmcnt never drains mid-loop
#pragma unroll 1
  for (int t = 0; t < 32; ++t) {
    const int sb = (t & 3) * 16384;
    const int u = t + 3;
    const unsigned short* As  = &lds[sb + aoff];
    const unsigned short* Bxs = &lds[sb + bxo];
    const unsigned short* Bfs = &lds[sb + bfo];
    const unsigned short* Brs = &lds[sb + bro];
    short8 ar[4], bx[2], bf[2], br2[2];
    // phase 0 reads: Bx,Bf + A; stage A,Bx of tile u
#pragma unroll
    for (int nj = 0; nj < 2; ++nj) {
      bx[nj] = *(const short8*)(Bxs + nj * 512);
      bf[nj] = *(const short8*)(Bfs + nj * 512);
    }
#pragma unroll
    for (int mi = 0; mi < 4; ++mi) ar[mi] = *(const short8*)(As + mi * 512);
    if (u < 32) {
      unsigned short* d = &lds[(u & 3) * 16384 + wave * 512];
      gl16(aSrc  + (size_t)u * 4096, d);
      gl16(bxSrc + (size_t)u * 4096, d + 4096);
    }
    __builtin_amdgcn_s_setprio(1);
#pragma unroll
    for (int mi = 0; mi < 4; ++mi)
#pragma unroll
      for (int nj = 0; nj < 2; ++nj) {
        ax[mi][nj] = __builtin_amdgcn_mfma_f32_16x16x32_bf16(ar[mi], bx[nj], ax[mi][nj], 0, 0, 0);
        af[mi][nj] = __builtin_amdgcn_mfma_f32_16x16x32_bf16(ar[mi], bf[nj], af[mi][nj], 0, 0, 0);
      }
    __builtin_amdgcn_s_setprio(0);
    // phase 1 reads: Br; stage Bf,Br of tile u
#pragma unroll
    for (int nj = 0; nj < 2; ++nj) br2[nj] = *(const short8*)(Brs + nj * 512);
    if (u < 32) {
      unsigned short* d = &lds[(u & 3) * 16384 + wave * 512];
      gl16(bfSrc + (size_t)u * 4096, d + 8192);
      gl16(brSrc + (size_t)u * 4096, d + 12288);
    }
    __builtin_amdgcn_s_setprio(1);
#pragma unroll
    for (int mi = 0; mi < 4; ++mi)
#pragma unroll
      for (int nj = 0; nj < 2; ++nj)
        arr[mi][nj] = __builtin_amdgcn_mfma_f32_16x16x32_bf16(ar[mi], br2[nj], arr[mi][nj], 0, 0, 0);
    __builtin_amdgcn_s_setprio(0);
    // counted boundary wait (tile t+1's 4 chunks landed); never 0 mid-loop
    if (t <= 28)      asm volatile("s_waitcnt vmcnt(8)" ::: "memory");
    else if (t == 29) asm volatile("s_waitcnt vmcnt(4)" ::: "memory");
    else if (t == 30) asm volatile("s_waitcnt vmcnt(0)" ::: "memory");
    barrier_fence();
  }

  // epilogue: C/D layout col=lane&15, row=(lane>>4)*4+reg [m89/m91-verified]
  // row = bm*128 + wm*64 + mi*16 + q*4 + rg = t*16 + b with
  //   t = bm*8 + wm*4 + mi (ascending in mi), b = q*4 + rg.
  const int q = lane >> 4, cc = lane & 15;
  const int h0 = bn * 128 + wn * 32 + cc;
  const int row0 = bm * 128 + wm * 64 + q * 4;
  float bbf[2], bbr[2];
#pragma unroll
  for (int nj = 0; nj < 2; ++nj) {
    bbf[nj] = bias[h0 + nj * 16];
    bbr[nj] = bias[1024 + h0 + nj * 16];
  }
  float pv[2][4], sv[2][4];
#pragma unroll
  for (int nj = 0; nj < 2; ++nj)
#pragma unroll
    for (int rg = 0; rg < 4; ++rg) {
      float p = 1.f, s = 0.f;
#pragma unroll
      for (int mi = 0; mi < 4; ++mi) {
        float xt = ax[mi][nj][rg];
        float f  = sigmoidf_(af[mi][nj][rg] + bbf[nj]);
        float rr = sigmoidf_(arr[mi][nj][rg] + bbr[nj]);
        const size_t ro = (size_t)(row0 + mi * 16 + rg) * 1024 + h0 + nj * 16;
        Xt[ro] = f32_to_bf16(xt);
        Fo[ro] = f32_to_bf16(f);
        Ro[ro] = f32_to_bf16(rr);
        s = f * s + (1.f - f) * xt;
        p *= f;
      }
      pv[nj][rg] = p; sv[nj][rg] = s;
    }
  // cross-wm combine via LDS (all staging drained; waves synced by K-loop)
  float* lf = (float*)lds;      // 4096 floats = 16 KB (slot 0, long dead)
  __syncthreads();
  if (wm == 0) {
#pragma unroll
    for (int nj = 0; nj < 2; ++nj)
#pragma unroll
      for (int rg = 0; rg < 4; ++rg) {
        const int idx = (((wn * 64 + lane) * 4 + rg) * 2 + nj) * 2;
        lf[idx]     = pv[nj][rg];
        lf[idx + 1] = sv[nj][rg];
      }
  }
  __syncthreads();
  if (wm == 1) {
#pragma unroll
    for (int nj = 0; nj < 2; ++nj)
#pragma unroll
      for (int rg = 0; rg < 4; ++rg) {
        const int idx = (((wn * 64 + lane) * 4 + rg) * 2 + nj) * 2;
        float plo = lf[idx], slo = lf[idx + 1];
        float phi = pv[nj][rg], shi = sv[nj][rg];
        const size_t off = (size_t)bm * NCH + (q * 4 + rg) * 1024 + h0 + nj * 16;
        Pseg1[off] = plo * phi;
        Sseg1[off] = phi * slo + shi;
      }
  }
}

// ------------------- layer-2 GEMM with fused segment scan -------------------
// R2 pipeline structure; 16-t segments (NSEG=128).  [R4 config, kept.]
__global__ __launch_bounds__(512, 2) void gemm2_scan(
    const unsigned short* __restrict__ A, const unsigned short* __restrict__ B,
    const float* __restrict__ bias, float* __restrict__ Pseg, float* __restrict__ Sseg)
{
  __shared__ unsigned short lds[65536];       // 128 KB = 4 ring slots x 32 KB
  const int tid = threadIdx.x;
  const int wave = tid >> 6, lane = tid & 63;
  const int wm = wave >> 2, wn = wave & 3;    // 2M x 4N wave grid
  const int id = blockIdx.x;                  // 1024 blocks
  const int xcd = id & 7, slot = id >> 3;     // 128 slots per xcd
  const int bn = slot >> 4;                   // 0..7
  const int bm = xcd * 16 + (slot & 15);      // 0..127

  const unsigned short* aSrc0 = A + ((size_t)(2 * bm + 0) * 32) * 4096 + tid * 8;
  const unsigned short* aSrc1 = A + ((size_t)(2 * bm + 1) * 32) * 4096 + tid * 8;
  const unsigned short* bxSrc = B + ((size_t)bn * 32) * 4096 + tid * 8;
  const unsigned short* bfSrc = B + ((size_t)(8 + bn) * 32) * 4096 + tid * 8;

  floatx4 ax[8][2], af[8][2];
#pragma unroll
  for (int i = 0; i < 8; i++)
#pragma unroll
    for (int j = 0; j < 2; j++)
#pragma unroll
      for (int rr = 0; rr < 4; rr++) { ax[i][j][rr] = 0.f; af[i][j][rr] = 0.f; }

  // prologue: stage K-tiles 0..2 (12 chunk-loads/wave), drain, barrier
#pragma unroll
  for (int u = 0; u < 3; ++u) {
    unsigned short* d = &lds[u * 16384 + wave * 512];
    gl16(aSrc0 + (size_t)u * 4096, d);
    gl16(aSrc1 + (size_t)u * 4096, d + 4096);
    gl16(bxSrc + (size_t)u * 4096, d + 8192);
    gl16(bfSrc + (size_t)u * 4096, d + 12288);
  }
  asm volatile("s_waitcnt vmcnt(0)" ::: "memory");
  barrier_fence();

  const int aoff  = wm * 4096 + lane * 8;            // A chunk = wm
  const int bxoff = 8192  + wn * 1024 + lane * 8;    // 2 frags per wave
  const int bfoff = 12288 + wn * 1024 + lane * 8;

  // main loop: one barrier per K-tile; vmcnt never drains mid-loop
#pragma unroll 1
  for (int t = 0; t < 32; ++t) {
    const int sb = (t & 3) * 16384;
    const int u = t + 3;
    const unsigned short* As  = &lds[sb + aoff];
    const unsigned short* Bxs = &lds[sb + bxoff];
    const unsigned short* Bfs = &lds[sb + bfoff];
    short8 bx[2], bf[2], ar[4];
    // phase 0 reads: Bx,Bf (2 each) + A(mi 0..3); stage A chunks of tile u
#pragma unroll
    for (int nj = 0; nj < 2; ++nj) {
      bx[nj] = *(const short8*)(Bxs + nj * 512);
      bf[nj] = *(const short8*)(Bfs + nj * 512);
    }
#pragma unroll
    for (int mi = 0; mi < 4; ++mi) ar[mi] = *(const short8*)(As + mi * 512);
    if (u < 32) {
      unsigned short* d = &lds[(u & 3) * 16384 + wave * 512];
      gl16(aSrc0 + (size_t)u * 4096, d);
      gl16(aSrc1 + (size_t)u * 4096, d + 4096);
    }
    __builtin_amdgcn_s_setprio(1);
#pragma unroll
    for (int mi = 0; mi < 4; ++mi)
#pragma unroll
      for (int nj = 0; nj < 2; ++nj) {
        ax[mi][nj] = __builtin_amdgcn_mfma_f32_16x16x32_bf16(ar[mi], bx[nj], ax[mi][nj], 0, 0, 0);
        af[mi][nj] = __builtin_amdgcn_mfma_f32_16x16x32_bf16(ar[mi], bf[nj], af[mi][nj], 0, 0, 0);
      }
    __builtin_amdgcn_s_setprio(0);
    // phase 1 reads: A(mi 4..7); stage B chunks of tile u
#pragma unroll
    for (int mi = 0; mi < 4; ++mi) ar[mi] = *(const short8*)(As + (4 + mi) * 512);
    if (u < 32) {
      unsigned short* d = &lds[(u & 3) * 16384 + wave * 512];
      gl16(bxSrc + (size_t)u * 4096, d + 8192);
      gl16(bfSrc + (size_t)u * 4096, d + 12288);
    }
    __builtin_amdgcn_s_setprio(1);
#pragma unroll
    for (int mi = 0; mi < 4; ++mi)
#pragma unroll
      for (int nj = 0; nj < 2; ++nj) {
        ax[4 + mi][nj] = __builtin_amdgcn_mfma_f32_16x16x32_bf16(ar[mi], bx[nj], ax[4 + mi][nj], 0, 0, 0);
        af[4 + mi][nj] = __builtin_amdgcn_mfma_f32_16x16x32_bf16(ar[mi], bf[nj], af[4 + mi][nj], 0, 0, 0);
      }
    __builtin_amdgcn_s_setprio(0);
    if (t <= 28)      asm volatile("s_waitcnt vmcnt(8)" ::: "memory");
    else if (t == 29) asm volatile("s_waitcnt vmcnt(4)" ::: "memory");
    else if (t == 30) asm volatile("s_waitcnt vmcnt(0)" ::: "memory");
    barrier_fence();
  }

  // epilogue: per (nj,rg): b = (lane>>4)*4+rg, h = bn*128+wn*32+nj*16+(lane&15),
  // t = bm*16 + wm*8 + mi.  8-step scan over mi; cross-wm combine via LDS.
  const int q = lane >> 4, cc = lane & 15;
  float pv[2][4], sv[2][4];
#pragma unroll
  for (int nj = 0; nj < 2; ++nj) {
    float bb = bias[bn * 128 + wn * 32 + nj * 16 + cc];
#pragma unroll
    for (int rg = 0; rg < 4; ++rg) {
      float p = 1.f, s = 0.f;
#pragma unroll
      for (int mi = 0; mi < 8; ++mi) {
        float f  = sigmoidf_(af[mi][nj][rg] + bb);
        float xt = ax[mi][nj][rg];
        s = f * s + (1.f - f) * xt;
        p *= f;
      }
      pv[nj][rg] = p; sv[nj][rg] = s;
    }
  }
  float* lf = (float*)lds;     // 4096 floats scratch
  __syncthreads();
  if (wm == 0) {
#pragma unroll
    for (int nj = 0; nj < 2; ++nj)
#pragma unroll
      for (int rg = 0; rg < 4; ++rg) {
        const int idx = (((wn * 64 + lane) * 4 + rg) * 2 + nj) * 2;
        lf[idx]     = pv[nj][rg];
        lf[idx + 1] = sv[nj][rg];
      }
  }
  __syncthreads();
  if (wm == 1) {
#pragma unroll
    for (int nj = 0; nj < 2; ++nj) {
      const int h = bn * 128 + wn * 32 + nj * 16 + cc;
#pragma unroll
      for (int rg = 0; rg < 4; ++rg) {
        const int idx = (((wn * 64 + lane) * 4 + rg) * 2 + nj) * 2;
        float plo = lf[idx], slo = lf[idx + 1];
        float phi = pv[nj][rg], shi = sv[nj][rg];
        const size_t off = (size_t)bm * NCH + (q * 4 + rg) * 1024 + h;
        Pseg[off] = plo * phi;
        Sseg[off] = phi * slo + shi;
      }
    }
  }
}

// ---------------- serial combine -> carries (layer 1), 1 ch/thread ----------
// 64 blocks, fully coalesced 4 B accesses; 256 segments of 8 t.
__global__ __launch_bounds__(256) void combine_c0(
    const float* __restrict__ P, const float* __restrict__ S, float* __restrict__ C0) {
  const int ch = blockIdx.x * 256 + threadIdx.x;
  float c = 0.f;
#pragma unroll 8
  for (int k = 0; k < NSEG1; ++k) {
    C0[(size_t)k * NCH + ch] = c;
    c = P[(size_t)k * NCH + ch] * c + S[(size_t)k * NCH + ch];
  }
}

// ------- pass 2 (layer 1): h1 = r*c + (1-r)*x, written DIRECTLY swizzled ----
// IN-PLACE: h1 overwrites xsw.  Block = (h-slab 128, 8-t segment), 2048 blocks.
#define TPAD 4112
__global__ __launch_bounds__(256) void scan1_pass2_fused(
    const unsigned short* __restrict__ Xt, const unsigned short* __restrict__ F,
    const unsigned short* __restrict__ R, unsigned short* __restrict__ xsw,
    const float* __restrict__ C0, unsigned short* __restrict__ h1last)
{
  __shared__ unsigned short st[4 * TPAD];
  const int hb = blockIdx.x;
  const int chunk = blockIdx.y;               // 0..255: 8-t segment
  const int tid = threadIdx.x;
  const int b = tid >> 4, hg = tid & 15;
  const int h0 = hb * 128 + hg * 8;
  const int ch = b * 1024 + h0;
  const int tl   = hg >> 2;
  const int usub = (hg & 3) * 16 + b;

  float c[8];
  {
    const float4* C4 = (const float4*)&C0[(size_t)chunk * NCH + ch];
    float4 a = C4[0], d = C4[1];
    c[0]=a.x; c[1]=a.y; c[2]=a.z; c[3]=a.w; c[4]=d.x; c[5]=d.y; c[6]=d.z; c[7]=d.w;
  }

  size_t idx = (size_t)chunk * 8 * NCH + ch;
#pragma unroll
  for (int ts = 0; ts < 8; ++ts) {
    const int t = chunk * 8 + ts;
    ushort8_t fv = *(const ushort8_t*)&F[idx];
    ushort8_t xv = *(const ushort8_t*)&Xt[idx];
    ushort8_t rv = *(const ushort8_t*)&R[idx];
    const size_t soff = ((size_t)(t >> 3) * 32 + (h0 >> 5)) * 4096
                      + (size_t)(((t & 7) * 64 + usub) * 8);
    ushort8_t xo = *(const ushort8_t*)&xsw[soff];
    ushort8_t hv;
#pragma unroll
    for (int j = 0; j < 8; ++j) {
      float f  = bf16_to_f32(fv[j]);
      float xt = bf16_to_f32(xv[j]);
      c[j] = f * c[j] + (1.f - f) * xt;
      float r  = bf16_to_f32(rv[j]);
      float xval = bf16_to_f32(xo[j]);
      hv[j] = f32_to_bf16(r * c[j] + (1.f - r) * xval);
    }
    *(ushort8_t*)&st[tl * TPAD + (ts * 64 + usub) * 8] = hv;
    if (t == SEQ - 1) *(ushort8_t*)&h1last[ch] = hv;
    idx += NCH;
  }
  __syncthreads();
  const size_t gbase = ((size_t)chunk * 32 + hb * 4) * 4096;
#pragma unroll
  for (int tl2 = 0; tl2 < 4; ++tl2) {
    size_t gdst = gbase + (size_t)tl2 * 4096 + tid * 16;
    *(ushort8_t*)&xsw[gdst]     = *(const ushort8_t*)&st[tl2 * TPAD + tid * 16];
    *(ushort8_t*)&xsw[gdst + 8] = *(const ushort8_t*)&st[tl2 * TPAD + tid * 16 + 8];
  }
}

// ------- r2 at last timestep: (16x1024) @ W1[:,2048:3072] fp32, 64 blocks ---
__global__ __launch_bounds__(256) void r2_kernel(
    const unsigned short* __restrict__ h1last, const float* __restrict__ W1,
    const float* __restrict__ b1, float* __restrict__ r2) {
  __shared__ float xrow[1024];
  const int b = blockIdx.x, nq = blockIdx.y, tid = threadIdx.x;
  for (int i = tid; i < 1024; i += 256)
    xrow[i] = bf16_to_f32(h1last[b * 1024 + i]);
  __syncthreads();
  const int n = nq * 256 + tid;
  float acc = b1[1024 + n];
  for (int d = 0; d < 1024; ++d)
    acc += xrow[d] * W1[(size_t)d * 3072 + 2048 + n];
  r2[b * 1024 + n] = sigmoidf_(acc);
}

// ------- layer-2: 128-segment serial combine + output, 1 ch/thread ----------
__global__ __launch_bounds__(256) void final_l2(
    const float* __restrict__ Pseg, const float* __restrict__ Sseg,
    const float* __restrict__ r2, const unsigned short* __restrict__ h1last,
    float* __restrict__ out) {
  const int ch = blockIdx.x * 256 + threadIdx.x;
  float c = 0.f;
#pragma unroll 8
  for (int k = 0; k < NSEG; ++k)
    c = Pseg[(size_t)k * NCH + ch] * c + Sseg[(size_t)k * NCH + ch];
  float r = r2[ch];
  float x = bf16_to_f32(h1last[ch]);
  out[ch] = r * c + (1.f - r) * x;
}

extern "C" void kernel_launch(void* const* d_in, const int* in_sizes, int n_in,
                              void* d_out, int out_size, void* d_ws, size_t ws_size,
                              hipStream_t stream) {
  const float* x  = (const float*)d_in[0];
  const float* W0 = (const float*)d_in[1];
  const float* b0 = (const float*)d_in[2];
  const float* W1 = (const float*)d_in[3];
  const float* b1 = (const float*)d_in[4];
  float* out = (float*)d_out;

  char* ws = (char*)d_ws;
  auto alloc = [&](size_t bytes) {
    char* p = ws; ws += (bytes + 255) & ~(size_t)255; return p;
  };
  const size_t NE = (size_t)M_TOT * HID;
  unsigned short* xsw   = (unsigned short*)alloc(NE * 2);   // x swizzled; h1 in-place
  unsigned short* W0sw  = (unsigned short*)alloc((size_t)3072 * 1024 * 2);
  unsigned short* W1sw  = (unsigned short*)alloc((size_t)3072 * 1024 * 2);
  unsigned short* Xt    = (unsigned short*)alloc(NE * 2);
  unsigned short* F     = (unsigned short*)alloc(NE * 2);
  unsigned short* R     = (unsigned short*)alloc(NE * 2);
  unsigned short* h1last= (unsigned short*)alloc((size_t)NCH * 2);
  float* Pseg1 = (float*)alloc((size_t)NSEG1 * NCH * 4);    // 16.8 MB
  float* Sseg1 = (float*)alloc((size_t)NSEG1 * NCH * 4);
  float* C0    = (float*)alloc((size_t)NSEG1 * NCH * 4);
  float* Pseg  = (float*)alloc((size_t)NSEG * NCH * 4);     // 8.4 MB
  float* Sseg  = (float*)alloc((size_t)NSEG * NCH * 4);
  float* r2    = (float*)alloc((size_t)NCH * 4);

  dim3 blk256(256);
  // 1. preprocessing: x->xsw, W0->W0sw, W1->W1sw
  prep_all<<<dim3(9728), blk256, 0, stream>>>(x, W0, W1, xsw, W0sw, W1sw);
  // 2. layer-1 GEMM (paired panels x/f/r) + fused 8-t segment scan
  gemm1_scan<<<dim3(2048), dim3(512), 0, stream>>>(xsw, W0sw, Xt, F, R, b0, Pseg1, Sseg1);
  // 3. 256-segment serial combine -> carries
  combine_c0<<<dim3(NCH / 256), blk256, 0, stream>>>(Pseg1, Sseg1, C0);
  // 4. pass 2: h1 written swizzled in-place (8-t segments)
  scan1_pass2_fused<<<dim3(8, NSEG1), blk256, 0, stream>>>(Xt, F, R, xsw, C0, h1last);
  // 5. r2 at last timestep
  r2_kernel<<<dim3(16, 4), blk256, 0, stream>>>(h1last, W1, b1, r2);
  // 6. layer-2 GEMM with fused segment scan (16-t segments)
  gemm2_scan<<<dim3(1024), dim3(512), 0, stream>>>(xsw, W1sw, b1, Pseg, Sseg);
  // 7. 128-segment combine + output
  final_l2<<<dim3(NCH / 256), blk256, 0, stream>>>(Pseg, Sseg, r2, h1last, out);
}

// Round 6
// 715.453 us; speedup vs baseline: 1.0849x; 1.0849x over previous
//
#include <hip/hip_runtime.h>

#define SEQ    2048
#define BATCH  16
#define HID    1024
#define M_TOT  (SEQ*BATCH)      // 32768 rows
#define NCH    (BATCH*HID)      // 16384 scan channels
#define NCHUNK 64
#define TCHUNK (SEQ/NCHUNK)     // 32 timesteps per chunk
#define NSEG   128              // layer-2: 16-timestep segments (one per gemm2 bm tile)

typedef __attribute__((ext_vector_type(8))) short          short8;
typedef __attribute__((ext_vector_type(8))) unsigned short ushort8_t;
typedef __attribute__((ext_vector_type(4))) float          floatx4;

__device__ __forceinline__ unsigned short f32_to_bf16(float f) {
  unsigned int u = __float_as_uint(f);
  u += 0x7FFFu + ((u >> 16) & 1u);           // round-to-nearest-even
  return (unsigned short)(u >> 16);
}
__device__ __forceinline__ float bf16_to_f32(unsigned short h) {
  return __uint_as_float(((unsigned int)h) << 16);
}
__device__ __forceinline__ float sigmoidf_(float x) {
  return 1.f / (1.f + __expf(-x));
}

// ============================================================================
// Swizzled operand layout ("fragment image"):
//   (R rows, K cols) bf16 -> blocks of 128 rows x 32 k = 4096 ushorts.
//   block = (row>>7)*(K/32) + (k>>5).  Within a block, for (r=row&127, kk=k&31):
//     unit = (r>>4)*64 + ((kk>>3)<<4) + (r&15);  ushort off = unit*8 + (kk&7)
//   MFMA fragment for rows j*16..j*16+15 = 1 KB at off j*512; lane l's 16B at
//   j*512 + l*8 -> direct global_load_dwordx4 / global_load_lds_dwordx4,
//   fully coalesced, and bank-conflict-free when re-read from LDS.
// ============================================================================

// ---------------- prep bodies (fused into one launch) -----------------------
__device__ __forceinline__ void cast_swizzle_body(const float* __restrict__ src,
    unsigned short* __restrict__ dst, int mt, int kt, int t) {
  __shared__ unsigned short tile[4096];
  const int r = t >> 1, kh = (t & 1) * 16;
  const float* sp = src + (size_t)(mt * 128 + r) * 1024 + kt * 32 + kh;
  float4 v0 = *(const float4*)(sp + 0);
  float4 v1 = *(const float4*)(sp + 4);
  float4 v2 = *(const float4*)(sp + 8);
  float4 v3 = *(const float4*)(sp + 12);
  ushort8_t u0, u1;
  u0[0]=f32_to_bf16(v0.x); u0[1]=f32_to_bf16(v0.y); u0[2]=f32_to_bf16(v0.z); u0[3]=f32_to_bf16(v0.w);
  u0[4]=f32_to_bf16(v1.x); u0[5]=f32_to_bf16(v1.y); u0[6]=f32_to_bf16(v1.z); u0[7]=f32_to_bf16(v1.w);
  u1[0]=f32_to_bf16(v2.x); u1[1]=f32_to_bf16(v2.y); u1[2]=f32_to_bf16(v2.z); u1[3]=f32_to_bf16(v2.w);
  u1[4]=f32_to_bf16(v3.x); u1[5]=f32_to_bf16(v3.y); u1[6]=f32_to_bf16(v3.z); u1[7]=f32_to_bf16(v3.w);
  const int c = r >> 4, lr = r & 15, q0 = kh >> 3;
  const int unit0 = c * 64 + (q0 << 4) + lr;
  *(ushort8_t*)&tile[unit0 * 8]        = u0;
  *(ushort8_t*)&tile[(unit0 + 16) * 8] = u1;
  __syncthreads();
  const size_t base = ((size_t)mt * 32 + kt) * 4096;
  *(ushort8_t*)&dst[base + t * 16]     = *(const ushort8_t*)&tile[t * 16];
  *(ushort8_t*)&dst[base + t * 16 + 8] = *(const ushort8_t*)&tile[t * 16 + 8];
}

__device__ __forceinline__ void w_prep_body(const float* __restrict__ W,
    unsigned short* __restrict__ Wsw, int nt, int kt, int t) {
  __shared__ unsigned short tile[4096];
  const int kk = t >> 3, n0 = (t & 7) * 16;
  const float* sp = W + (size_t)(kt * 32 + kk) * 3072 + nt * 128 + n0;
  float v[16];
#pragma unroll
  for (int i = 0; i < 16; i += 4) {
    float4 f = *(const float4*)(sp + i);
    v[i] = f.x; v[i+1] = f.y; v[i+2] = f.z; v[i+3] = f.w;
  }
  const int cbase = (n0 >> 4) * 64 + ((kk >> 3) << 4);
#pragma unroll
  for (int j = 0; j < 16; j++)
    tile[(cbase + j) * 8 + (kk & 7)] = f32_to_bf16(v[j]);
  __syncthreads();
  const size_t base = ((size_t)nt * 32 + kt) * 4096;
  *(ushort8_t*)&Wsw[base + t * 16]     = *(const ushort8_t*)&tile[t * 16];
  *(ushort8_t*)&Wsw[base + t * 16 + 8] = *(const ushort8_t*)&tile[t * 16 + 8];
}

// one launch: blocks [0,8192) cast x; [8192,8960) W0; [8960,9728) W1
__global__ __launch_bounds__(256) void prep_all(const float* __restrict__ x,
    const float* __restrict__ W0, const float* __restrict__ W1,
    unsigned short* __restrict__ xsw, unsigned short* __restrict__ W0sw,
    unsigned short* __restrict__ W1sw) {
  const int id = blockIdx.x, t = threadIdx.x;
  if (id < 8192)        cast_swizzle_body(x, xsw, id >> 5, id & 31, t);
  else if (id < 8960)   w_prep_body(W0, W0sw, (id - 8192) >> 5, (id - 8192) & 31, t);
  else                  w_prep_body(W1, W1sw, (id - 8960) >> 5, (id - 8960) & 31, t);
}

// ---------------------------------------------------------------------------
// global_load_lds helper: 16B per lane, wave-uniform LDS base + lane*16 (HW).
// ---------------------------------------------------------------------------
typedef __attribute__((address_space(1))) const unsigned int GUI;
typedef __attribute__((address_space(3))) unsigned int LUI;
__device__ __forceinline__ void gl16(const unsigned short* g, unsigned short* l) {
  __builtin_amdgcn_global_load_lds((GUI*)g, (LUI*)l, 16, 0, 0);
}
// barrier as inline asm with memory clobber: scheduling fence for LDS ops,
// and (unlike __syncthreads) no compiler-inserted vmcnt(0) drain.
__device__ __forceinline__ void barrier_fence() {
  asm volatile("s_barrier" ::: "memory");
}

// ---------------------------------------------------------------------------
// Layer-1 GEMM, LDS-pipelined, SINGLE barrier per K-tile.  [R2/R4 config —
// best measured: 226 µs, FETCH 147.7 MB, WRITE 196.6 MB, 0 conflicts.
// R3 (2-resident, BN=128) and R5 (paired-panel fusion) both regressed.]
//   Tile 256x256, BK=32, 8 waves (2M x 4N), wave tile 128x64, acc 8x4 frags.
//   LDS ring: 4 slots x 32KB.  Stage 3 K-tiles ahead; counted vmcnt(8)
//   boundary (never 0 mid-loop); one s_barrier per K-tile.
// ---------------------------------------------------------------------------
__global__ __launch_bounds__(512, 2) void gemm_pipe(
    const unsigned short* __restrict__ A, const unsigned short* __restrict__ B,
    unsigned short* __restrict__ Xt, unsigned short* __restrict__ Fo,
    unsigned short* __restrict__ Ro, const float* __restrict__ bias)
{
  __shared__ unsigned short lds[65536];       // 128 KB = 4 ring slots x 32 KB
  const int tid = threadIdx.x;
  const int wave = tid >> 6, lane = tid & 63;
  const int wm = wave >> 2, wn = wave & 3;    // 2M x 4N wave grid
  const int id = blockIdx.x;
  // XCD-chunked swizzle: 16 bm-tiles per XCD, groups of (8 bm x 12 bn),
  // bm fastest -> B panel resident, A slab (8 x 512KB = 4MB) cycling in L2.
  const int xcd = id & 7, slot = id >> 3;     // 192 slots per xcd
  const int g = slot / 96, r = slot % 96;
  const int bn = r >> 3;                      // 0..11
  const int bm = xcd * 16 + g * 8 + (r & 7);  // 0..127

  // staging source pointers (per-lane 16B piece of each 8KB chunk)
  const unsigned short* aSrc0 = A + ((size_t)(2 * bm + 0) * 32) * 4096 + tid * 8;
  const unsigned short* aSrc1 = A + ((size_t)(2 * bm + 1) * 32) * 4096 + tid * 8;
  const unsigned short* bSrc0 = B + ((size_t)(2 * bn + 0) * 32) * 4096 + tid * 8;
  const unsigned short* bSrc1 = B + ((size_t)(2 * bn + 1) * 32) * 4096 + tid * 8;

  floatx4 acc[8][4];
#pragma unroll
  for (int i = 0; i < 8; i++)
#pragma unroll
    for (int j = 0; j < 4; j++)
#pragma unroll
      for (int rr = 0; rr < 4; rr++) acc[i][j][rr] = 0.f;

  // prologue: stage K-tiles 0..2 (12 chunk-loads/wave), drain, barrier
#pragma unroll
  for (int u = 0; u < 3; ++u) {
    unsigned short* d = &lds[u * 16384 + wave * 512];
    gl16(aSrc0 + (size_t)u * 4096, d);
    gl16(aSrc1 + (size_t)u * 4096, d + 4096);
    gl16(bSrc0 + (size_t)u * 4096, d + 8192);
    gl16(bSrc1 + (size_t)u * 4096, d + 12288);
  }
  asm volatile("s_waitcnt vmcnt(0)" ::: "memory");
  barrier_fence();

  const int aoff = wm * 4096 + lane * 8;                       // chunk rb = wm
  const int boff = 8192 + (wn >> 1) * 4096 + (wn & 1) * 2048 + lane * 8;

  // main loop: one barrier per K-tile
#pragma unroll 1
  for (int t = 0; t < 32; ++t) {
    const int sb = (t & 3) * 16384;
    const int u = t + 3;
    const unsigned short* As = &lds[sb + aoff];
    const unsigned short* Bs = &lds[sb + boff];
    short8 br[4], ar[4];
    // phase 0 reads: B(all 4) + A(mi 0..3); stage A chunks of tile u
#pragma unroll
    for (int nj = 0; nj < 4; ++nj) br[nj] = *(const short8*)(Bs + nj * 512);
#pragma unroll
    for (int mi = 0; mi < 4; ++mi) ar[mi] = *(const short8*)(As + mi * 512);
    if (u < 32) {
      unsigned short* d = &lds[(u & 3) * 16384 + wave * 512];
      gl16(aSrc0 + (size_t)u * 4096, d);
      gl16(aSrc1 + (size_t)u * 4096, d + 4096);
    }
    __builtin_amdgcn_s_setprio(1);
#pragma unroll
    for (int mi = 0; mi < 4; ++mi)
#pragma unroll
      for (int nj = 0; nj < 4; ++nj)
        acc[mi][nj] = __builtin_amdgcn_mfma_f32_16x16x32_bf16(ar[mi], br[nj], acc[mi][nj], 0, 0, 0);
    __builtin_amdgcn_s_setprio(0);
    // phase 1 reads: A(mi 4..7); stage B chunk of tile u
#pragma unroll
    for (int mi = 0; mi < 4; ++mi) ar[mi] = *(const short8*)(As + (4 + mi) * 512);
    if (u < 32) {
      unsigned short* d = &lds[(u & 3) * 16384 + wave * 512];
      gl16(bSrc0 + (size_t)u * 4096, d + 8192);
      gl16(bSrc1 + (size_t)u * 4096, d + 12288);
    }
    __builtin_amdgcn_s_setprio(1);
#pragma unroll
    for (int mi = 0; mi < 4; ++mi)
#pragma unroll
      for (int nj = 0; nj < 4; ++nj)
        acc[4 + mi][nj] = __builtin_amdgcn_mfma_f32_16x16x32_bf16(ar[mi], br[nj], acc[4 + mi][nj], 0, 0, 0);
    __builtin_amdgcn_s_setprio(0);
    // counted boundary wait (tile t+1's chunks landed); never 0 mid-loop
    if (t <= 28)      asm volatile("s_waitcnt vmcnt(8)" ::: "memory");
    else if (t == 29) asm volatile("s_waitcnt vmcnt(4)" ::: "memory");
    else if (t == 30) asm volatile("s_waitcnt vmcnt(0)" ::: "memory");
    barrier_fence();
  }

  // epilogue: C/D layout col=lane&15, row=(lane>>4)*4+reg  [m89/m91-verified]
  // nj innermost -> contiguous 128B runs per (mi,rg): L2 write-combining.
  const int region = bn >> 2;                  // block-uniform (BN=256)
  const int cc = lane & 15, q = lane >> 4;
  const int lc0 = (bn & 3) * 256 + wn * 64 + cc;
  const int row0 = bm * 256 + wm * 128 + q * 4;
  if (region == 0) {
#pragma unroll
    for (int mi = 0; mi < 8; ++mi)
#pragma unroll
      for (int rg = 0; rg < 4; ++rg)
#pragma unroll
        for (int nj = 0; nj < 4; ++nj)
          Xt[(size_t)(row0 + mi * 16 + rg) * 1024 + lc0 + nj * 16] =
              f32_to_bf16(acc[mi][nj][rg]);
  } else {
    unsigned short* O = (region == 1) ? Fo : Ro;
    const float* bp = bias + (region - 1) * 1024;
    float bb[4];
#pragma unroll
    for (int nj = 0; nj < 4; ++nj) bb[nj] = bp[lc0 + nj * 16];
#pragma unroll
    for (int mi = 0; mi < 8; ++mi)
#pragma unroll
      for (int rg = 0; rg < 4; ++rg)
#pragma unroll
        for (int nj = 0; nj < 4; ++nj) {
          float s = sigmoidf_(acc[mi][nj][rg] + bb[nj]);
          O[(size_t)(row0 + mi * 16 + rg) * 1024 + lc0 + nj * 16] = f32_to_bf16(s);
        }
  }
}

// ------------------- layer-2 GEMM with fused segment scan -------------------
// R2 pipeline structure; 16-t segments (NSEG=128).  [R4 config, kept.]
__global__ __launch_bounds__(512, 2) void gemm2_scan(
    const unsigned short* __restrict__ A, const unsigned short* __restrict__ B,
    const float* __restrict__ bias, float* __restrict__ Pseg, float* __restrict__ Sseg)
{
  __shared__ unsigned short lds[65536];       // 128 KB = 4 ring slots x 32 KB
  const int tid = threadIdx.x;
  const int wave = tid >> 6, lane = tid & 63;
  const int wm = wave >> 2, wn = wave & 3;    // 2M x 4N wave grid
  const int id = blockIdx.x;                  // 1024 blocks
  const int xcd = id & 7, slot = id >> 3;     // 128 slots per xcd
  const int bn = slot >> 4;                   // 0..7
  const int bm = xcd * 16 + (slot & 15);      // 0..127

  const unsigned short* aSrc0 = A + ((size_t)(2 * bm + 0) * 32) * 4096 + tid * 8;
  const unsigned short* aSrc1 = A + ((size_t)(2 * bm + 1) * 32) * 4096 + tid * 8;
  const unsigned short* bxSrc = B + ((size_t)bn * 32) * 4096 + tid * 8;
  const unsigned short* bfSrc = B + ((size_t)(8 + bn) * 32) * 4096 + tid * 8;

  floatx4 ax[8][2], af[8][2];
#pragma unroll
  for (int i = 0; i < 8; i++)
#pragma unroll
    for (int j = 0; j < 2; j++)
#pragma unroll
      for (int rr = 0; rr < 4; rr++) { ax[i][j][rr] = 0.f; af[i][j][rr] = 0.f; }

  // prologue: stage K-tiles 0..2 (12 chunk-loads/wave), drain, barrier
#pragma unroll
  for (int u = 0; u < 3; ++u) {
    unsigned short* d = &lds[u * 16384 + wave * 512];
    gl16(aSrc0 + (size_t)u * 4096, d);
    gl16(aSrc1 + (size_t)u * 4096, d + 4096);
    gl16(bxSrc + (size_t)u * 4096, d + 8192);
    gl16(bfSrc + (size_t)u * 4096, d + 12288);
  }
  asm volatile("s_waitcnt vmcnt(0)" ::: "memory");
  barrier_fence();

  const int aoff  = wm * 4096 + lane * 8;            // A chunk = wm
  const int bxoff = 8192  + wn * 1024 + lane * 8;    // 2 frags per wave
  const int bfoff = 12288 + wn * 1024 + lane * 8;

  // main loop: one barrier per K-tile; vmcnt never drains mid-loop
#pragma unroll 1
  for (int t = 0; t < 32; ++t) {
    const int sb = (t & 3) * 16384;
    const int u = t + 3;
    const unsigned short* As  = &lds[sb + aoff];
    const unsigned short* Bxs = &lds[sb + bxoff];
    const unsigned short* Bfs = &lds[sb + bfoff];
    short8 bx[2], bf[2], ar[4];
    // phase 0 reads: Bx,Bf (2 each) + A(mi 0..3); stage A chunks of tile u
#pragma unroll
    for (int nj = 0; nj < 2; ++nj) {
      bx[nj] = *(const short8*)(Bxs + nj * 512);
      bf[nj] = *(const short8*)(Bfs + nj * 512);
    }
#pragma unroll
    for (int mi = 0; mi < 4; ++mi) ar[mi] = *(const short8*)(As + mi * 512);
    if (u < 32) {
      unsigned short* d = &lds[(u & 3) * 16384 + wave * 512];
      gl16(aSrc0 + (size_t)u * 4096, d);
      gl16(aSrc1 + (size_t)u * 4096, d + 4096);
    }
    __builtin_amdgcn_s_setprio(1);
#pragma unroll
    for (int mi = 0; mi < 4; ++mi)
#pragma unroll
      for (int nj = 0; nj < 2; ++nj) {
        ax[mi][nj] = __builtin_amdgcn_mfma_f32_16x16x32_bf16(ar[mi], bx[nj], ax[mi][nj], 0, 0, 0);
        af[mi][nj] = __builtin_amdgcn_mfma_f32_16x16x32_bf16(ar[mi], bf[nj], af[mi][nj], 0, 0, 0);
      }
    __builtin_amdgcn_s_setprio(0);
    // phase 1 reads: A(mi 4..7); stage B chunks of tile u
#pragma unroll
    for (int mi = 0; mi < 4; ++mi) ar[mi] = *(const short8*)(As + (4 + mi) * 512);
    if (u < 32) {
      unsigned short* d = &lds[(u & 3) * 16384 + wave * 512];
      gl16(bxSrc + (size_t)u * 4096, d + 8192);
      gl16(bfSrc + (size_t)u * 4096, d + 12288);
    }
    __builtin_amdgcn_s_setprio(1);
#pragma unroll
    for (int mi = 0; mi < 4; ++mi)
#pragma unroll
      for (int nj = 0; nj < 2; ++nj) {
        ax[4 + mi][nj] = __builtin_amdgcn_mfma_f32_16x16x32_bf16(ar[mi], bx[nj], ax[4 + mi][nj], 0, 0, 0);
        af[4 + mi][nj] = __builtin_amdgcn_mfma_f32_16x16x32_bf16(ar[mi], bf[nj], af[4 + mi][nj], 0, 0, 0);
      }
    __builtin_amdgcn_s_setprio(0);
    if (t <= 28)      asm volatile("s_waitcnt vmcnt(8)" ::: "memory");
    else if (t == 29) asm volatile("s_waitcnt vmcnt(4)" ::: "memory");
    else if (t == 30) asm volatile("s_waitcnt vmcnt(0)" ::: "memory");
    barrier_fence();
  }

  // epilogue: per (nj,rg): b = (lane>>4)*4+rg, h = bn*128+wn*32+nj*16+(lane&15),
  // t = bm*16 + wm*8 + mi.  8-step scan over mi; cross-wm combine via LDS.
  const int q = lane >> 4, cc = lane & 15;
  float pv[2][4], sv[2][4];
#pragma unroll
  for (int nj = 0; nj < 2; ++nj) {
    float bb = bias[bn * 128 + wn * 32 + nj * 16 + cc];
#pragma unroll
    for (int rg = 0; rg < 4; ++rg) {
      float p = 1.f, s = 0.f;
#pragma unroll
      for (int mi = 0; mi < 8; ++mi) {
        float f  = sigmoidf_(af[mi][nj][rg] + bb);
        float xt = ax[mi][nj][rg];
        s = f * s + (1.f - f) * xt;
        p *= f;
      }
      pv[nj][rg] = p; sv[nj][rg] = s;
    }
  }
  float* lf = (float*)lds;     // 4096 floats scratch
  __syncthreads();
  if (wm == 0) {
#pragma unroll
    for (int nj = 0; nj < 2; ++nj)
#pragma unroll
      for (int rg = 0; rg < 4; ++rg) {
        const int idx = (((wn * 64 + lane) * 4 + rg) * 2 + nj) * 2;
        lf[idx]     = pv[nj][rg];
        lf[idx + 1] = sv[nj][rg];
      }
  }
  __syncthreads();
  if (wm == 1) {
#pragma unroll
    for (int nj = 0; nj < 2; ++nj) {
      const int h = bn * 128 + wn * 32 + nj * 16 + cc;
#pragma unroll
      for (int rg = 0; rg < 4; ++rg) {
        const int idx = (((wn * 64 + lane) * 4 + rg) * 2 + nj) * 2;
        float plo = lf[idx], slo = lf[idx + 1];
        float phi = pv[nj][rg], shi = sv[nj][rg];
        const size_t off = (size_t)bm * NCH + (q * 4 + rg) * 1024 + h;
        Pseg[off] = plo * phi;
        Sseg[off] = phi * slo + shi;
      }
    }
  }
}

// ---------------- blocked scan pass 1 (layer 1), 8 channels/thread ----------
// 64 chunks of 32 timesteps -> 512 blocks (2/CU), serial depth 32.
__global__ __launch_bounds__(256) void scan_pass1(
    const unsigned short* __restrict__ Xt, const unsigned short* __restrict__ F,
    float* __restrict__ P, float* __restrict__ S) {
  const int ch = (blockIdx.x * 256 + threadIdx.x) * 8;
  const int chunk = blockIdx.y;
  size_t idx = (size_t)chunk * TCHUNK * NCH + ch;
  float p[8], s[8];
#pragma unroll
  for (int j = 0; j < 8; j++) { p[j] = 1.f; s[j] = 0.f; }
  for (int t = 0; t < TCHUNK; ++t) {
    ushort8_t fv = *(const ushort8_t*)&F[idx];
    ushort8_t xv = *(const ushort8_t*)&Xt[idx];
#pragma unroll
    for (int j = 0; j < 8; j++) {
      float f  = bf16_to_f32(fv[j]);
      float xt = bf16_to_f32(xv[j]);
      s[j] = f * s[j] + (1.f - f) * xt;
      p[j] *= f;
    }
    idx += NCH;
  }
  float4* P4 = (float4*)&P[(size_t)chunk * NCH + ch];
  float4* S4 = (float4*)&S[(size_t)chunk * NCH + ch];
  P4[0] = make_float4(p[0], p[1], p[2], p[3]);
  P4[1] = make_float4(p[4], p[5], p[6], p[7]);
  S4[0] = make_float4(s[0], s[1], s[2], s[3]);
  S4[1] = make_float4(s[4], s[5], s[6], s[7]);
}

// ---------------- serial combine -> carries (layer 1), 1 ch/thread ----------
// 64 blocks, fully coalesced 4 B accesses.
__global__ __launch_bounds__(256) void combine_c0(
    const float* __restrict__ P, const float* __restrict__ S, float* __restrict__ C0) {
  const int ch = blockIdx.x * 256 + threadIdx.x;
  float c = 0.f;
#pragma unroll 4
  for (int k = 0; k < NCHUNK; ++k) {
    C0[(size_t)k * NCH + ch] = c;
    c = P[(size_t)k * NCH + ch] * c + S[(size_t)k * NCH + ch];
  }
}

// ------- pass 2 (layer 1): h1 = r*c + (1-r)*x, written DIRECTLY swizzled ----
// IN-PLACE: h1 overwrites xsw.  Block = (h-slab 128, chunk of 32 t), 512 blocks.
#define TPAD 4112
__global__ __launch_bounds__(256) void scan1_pass2_fused(
    const unsigned short* __restrict__ Xt, const unsigned short* __restrict__ F,
    const unsigned short* __restrict__ R, unsigned short* __restrict__ xsw,
    const float* __restrict__ C0, unsigned short* __restrict__ h1last)
{
  __shared__ unsigned short st[4 * TPAD];
  const int hb = blockIdx.x;
  const int chunk = blockIdx.y;
  const int tid = threadIdx.x;
  const int b = tid >> 4, hg = tid & 15;
  const int h0 = hb * 128 + hg * 8;
  const int ch = b * 1024 + h0;
  const int tl   = hg >> 2;
  const int usub = (hg & 3) * 16 + b;

  float c[8];
  {
    const float4* C4 = (const float4*)&C0[(size_t)chunk * NCH + ch];
    float4 a = C4[0], d = C4[1];
    c[0]=a.x; c[1]=a.y; c[2]=a.z; c[3]=a.w; c[4]=d.x; c[5]=d.y; c[6]=d.z; c[7]=d.w;
  }

  size_t idx = (size_t)chunk * TCHUNK * NCH + ch;
  for (int t8 = 0; t8 < TCHUNK / 8; ++t8) {
#pragma unroll
    for (int ts = 0; ts < 8; ++ts) {
      const int t = chunk * TCHUNK + t8 * 8 + ts;
      ushort8_t fv = *(const ushort8_t*)&F[idx];
      ushort8_t xv = *(const ushort8_t*)&Xt[idx];
      ushort8_t rv = *(const ushort8_t*)&R[idx];
      const size_t soff = ((size_t)(t >> 3) * 32 + (h0 >> 5)) * 4096
                        + (size_t)(((t & 7) * 64 + usub) * 8);
      ushort8_t xo = *(const ushort8_t*)&xsw[soff];
      ushort8_t hv;
#pragma unroll
      for (int j = 0; j < 8; ++j) {
        float f  = bf16_to_f32(fv[j]);
        float xt = bf16_to_f32(xv[j]);
        c[j] = f * c[j] + (1.f - f) * xt;
        float r  = bf16_to_f32(rv[j]);
        float xval = bf16_to_f32(xo[j]);
        hv[j] = f32_to_bf16(r * c[j] + (1.f - r) * xval);
      }
      *(ushort8_t*)&st[tl * TPAD + (ts * 64 + usub) * 8] = hv;
      if (t == SEQ - 1) *(ushort8_t*)&h1last[ch] = hv;
      idx += NCH;
    }
    __syncthreads();
    const size_t gbase = (((size_t)chunk * (TCHUNK / 8) + t8) * 32 + hb * 4) * 4096;
#pragma unroll
    for (int tl2 = 0; tl2 < 4; ++tl2) {
      size_t gdst = gbase + (size_t)tl2 * 4096 + tid * 16;
      *(ushort8_t*)&xsw[gdst]     = *(const ushort8_t*)&st[tl2 * TPAD + tid * 16];
      *(ushort8_t*)&xsw[gdst + 8] = *(const ushort8_t*)&st[tl2 * TPAD + tid * 16 + 8];
    }
    __syncthreads();
  }
}

// ------- layer-2: 128-segment combine + fused r2 GEMM + output --------------
// 64 blocks x 256 threads; block covers one batch b (4 blocks per b share
// the same h1last row staged in LDS).  r2 = sigmoid(b1r + h1last[b,:]·W1col)
// computed alongside the latency-bound 128-step combine chain (fills its
// ALU shadow); W1 col slice (4 MB) is L2-resident after the first blocks.
__global__ __launch_bounds__(256) void final_l2(
    const float* __restrict__ Pseg, const float* __restrict__ Sseg,
    const unsigned short* __restrict__ h1last, const float* __restrict__ W1,
    const float* __restrict__ b1, float* __restrict__ out) {
  __shared__ float xrow[1024];
  const int ch = blockIdx.x * 256 + threadIdx.x;
  const int b = ch >> 10;                     // uniform per block
  const int n = ch & 1023;
  for (int i = threadIdx.x; i < 1024; i += 256)
    xrow[i] = bf16_to_f32(h1last[b * 1024 + i]);
  __syncthreads();
  // r2 dot product (independent FMA stream)
  float racc = b1[1024 + n];
  for (int d = 0; d < 1024; ++d)
    racc += xrow[d] * W1[(size_t)d * 3072 + 2048 + n];
  const float r = sigmoidf_(racc);
  // 128-segment serial combine (dependent chain)
  float c = 0.f;
#pragma unroll 8
  for (int k = 0; k < NSEG; ++k)
    c = Pseg[(size_t)k * NCH + ch] * c + Sseg[(size_t)k * NCH + ch];
  out[ch] = r * c + (1.f - r) * xrow[n];
}

extern "C" void kernel_launch(void* const* d_in, const int* in_sizes, int n_in,
                              void* d_out, int out_size, void* d_ws, size_t ws_size,
                              hipStream_t stream) {
  const float* x  = (const float*)d_in[0];
  const float* W0 = (const float*)d_in[1];
  const float* b0 = (const float*)d_in[2];
  const float* W1 = (const float*)d_in[3];
  const float* b1 = (const float*)d_in[4];
  float* out = (float*)d_out;

  char* ws = (char*)d_ws;
  auto alloc = [&](size_t bytes) {
    char* p = ws; ws += (bytes + 255) & ~(size_t)255; return p;
  };
  const size_t NE = (size_t)M_TOT * HID;
  unsigned short* xsw   = (unsigned short*)alloc(NE * 2);   // x swizzled; h1 in-place
  unsigned short* W0sw  = (unsigned short*)alloc((size_t)3072 * 1024 * 2);
  unsigned short* W1sw  = (unsigned short*)alloc((size_t)3072 * 1024 * 2);
  unsigned short* Xt    = (unsigned short*)alloc(NE * 2);
  unsigned short* F     = (unsigned short*)alloc(NE * 2);
  unsigned short* R     = (unsigned short*)alloc(NE * 2);
  unsigned short* h1last= (unsigned short*)alloc((size_t)NCH * 2);
  float* P    = (float*)alloc((size_t)NCHUNK * NCH * 4);
  float* S    = (float*)alloc((size_t)NCHUNK * NCH * 4);
  float* C0   = (float*)alloc((size_t)NCHUNK * NCH * 4);
  float* Pseg = (float*)alloc((size_t)NSEG * NCH * 4);      // 8.4 MB
  float* Sseg = (float*)alloc((size_t)NSEG * NCH * 4);

  dim3 blk256(256);
  // 1. preprocessing: x->xsw, W0->W0sw, W1->W1sw
  prep_all<<<dim3(9728), blk256, 0, stream>>>(x, W0, W1, xsw, W0sw, W1sw);
  // 2. layer-1 GEMM: 256x256 tiles, 4-slot LDS ring, 1 barrier/K-tile (R2/R4)
  gemm_pipe<<<dim3(1536), dim3(512), 0, stream>>>(xsw, W0sw, Xt, F, R, b0);
  // 3. blocked scan layer 1 (64 chunks x 32 t)
  scan_pass1<<<dim3(8, NCHUNK), blk256, 0, stream>>>(Xt, F, P, S);
  combine_c0<<<dim3(NCH / 256), blk256, 0, stream>>>(P, S, C0);
  scan1_pass2_fused<<<dim3(8, NCHUNK), blk256, 0, stream>>>(Xt, F, R, xsw, C0, h1last);
  // 4. layer-2 GEMM with fused segment scan, R2-pipelined (16-t segments)
  gemm2_scan<<<dim3(1024), dim3(512), 0, stream>>>(xsw, W1sw, b1, Pseg, Sseg);
  // 5. 128-segment combine + fused r2 + output (64 blocks)
  final_l2<<<dim3(NCH / 256), blk256, 0, stream>>>(Pseg, Sseg, h1last, W1, b1, out);
}